// Round 11
// baseline (232.434 us; speedup 1.0000x reference)
//
#include <hip/hip_runtime.h>
#include <hip/hip_bf16.h>
#include <math.h>

#define Bx 8
#define Cx 512
#define Dx 256
#define Tx 2048
#define EPSx 1e-5f

typedef _Float16 h16;
typedef __attribute__((ext_vector_type(8))) _Float16 h16x8;
typedef __attribute__((ext_vector_type(8))) short s16x8;
typedef __attribute__((ext_vector_type(4))) float f32x4;

typedef __attribute__((address_space(3))) unsigned int lds_u32;
typedef __attribute__((address_space(1))) const unsigned int glb_u32;

// async 16B global -> LDS DMA. ldsp must be wave-uniform; HW adds lane*16.
__device__ __forceinline__ void cp16(void* ldsp, const void* g) {
    __builtin_amdgcn_global_load_lds((glb_u32*)g, (lds_u32*)ldsp, 16, 0, 0);
}

// ---------------------------------------------------------------------------
// MFMA GEMM core: acc[m][n] = sum_k A[m][k]*B[n][k], 2-byte dtypes (f16/bf16),
// tile 128 x TN, K-chunk BKt, 4 waves (2x2), global_load_lds staging with
// width-matched XOR swizzle (stored_chunk = logical ^ (row & (CH-1))).
// r10 verified: BKt=128 4-bit XOR -> 0 conflicts.
// Grid: 1-D, batch->XCD swizzle b = id & 7 (r7: FETCH 147->41MB).
// Epilogue by MODE:
//   0: f16 out, + optional biasM[row] + biasN[col]                (projection)
//   1: bf16 out = acc * (1/Z[b*N+col])                            (gh' = gh/Z)
//   2: bf16 out = exp(acc); atomicAdd Z[b*N+col] += col sums      (logits)
//   3: f16 out = acc + biasN[col]; atomicAdd Cp[col]+=sum(v),
//      Z[col]+=sum(v^2) (fused BatchNorm stats)                   (big GEMM)
// ---------------------------------------------------------------------------
template<int MODE, bool BF, int TN, int BKt>
__global__ __launch_bounds__(256, 4)
void gemm_mf(const h16* __restrict__ A, long aBatch, int lda,
             const h16* __restrict__ B, long bBatch, int ldb,
             void* __restrict__ C, long cBatch, int ldc,
             float* __restrict__ Cp, float* __restrict__ Z,
             int M, int N, int K, int mBlk,
             const float* __restrict__ biasM, const float* __restrict__ biasN) {
    constexpr int NJ  = TN / 32;         // B-frags per wave (n-dir)
    constexpr int CH  = BKt / 8;         // 16B chunks per LDS row
    constexpr int RPR = 2048 / BKt;      // rows per 4KB staging round
    __shared__ h16 As[128 * BKt];
    __shared__ h16 Bs[TN * BKt];
    const int tid  = threadIdx.x;
    const int lane = tid & 63, wid = tid >> 6;
    const int wm = (wid & 1) * 64, wn = (wid >> 1) * (TN / 2);
    const int lm = lane & 15, quad = lane >> 4;
    const unsigned id = blockIdx.x;
    const int b = id & 7;
    const unsigned rr = id >> 3;
    const int m0 = (rr % (unsigned)mBlk) * 128;
    const int n0 = (rr / (unsigned)mBlk) * TN;
    const h16* Ab = A + (size_t)b * aBatch + (size_t)m0 * lda;
    const h16* Bb = B + (size_t)b * bBatch + (size_t)n0 * ldb;

    const int srow  = tid / CH;                        // row within round
    const int sclog = (tid & (CH - 1)) ^ (srow & (CH - 1));  // logical chunk
    char* ldsA = (char*)As + (tid & ~63) * 16;         // wave-uniform base
    char* ldsB = (char*)Bs + (tid & ~63) * 16;

    f32x4 acc[4][NJ] = {};

    for (int k0 = 0; k0 < K; k0 += BKt) {
        __syncthreads();   // all waves done reading previous tile
#pragma unroll
        for (int i = 0; i < 128 / RPR; i++) {
            int r = srow + RPR * i;
            cp16(ldsA + i * 4096, Ab + (size_t)r * lda + k0 + sclog * 8);
        }
#pragma unroll
        for (int i = 0; i < TN / RPR; i++) {
            int r = srow + RPR * i;
            cp16(ldsB + i * 4096, Bb + (size_t)r * ldb + k0 + sclog * 8);
        }
        __syncthreads();   // drains vmcnt(0): tile resident
#pragma unroll
        for (int ks = 0; ks < BKt / 32; ks++) {
            s16x8 af[4], bf4[NJ];
#pragma unroll
            for (int i = 0; i < 4; i++) {
                int row = wm + 16 * i + lm;
                int st = (ks * 4 + quad) ^ (lm & (CH - 1));
                af[i] = *(const s16x8*)(As + row * BKt + st * 8);
            }
#pragma unroll
            for (int j = 0; j < NJ; j++) {
                int row = wn + 16 * j + lm;
                int st = (ks * 4 + quad) ^ (lm & (CH - 1));
                bf4[j] = *(const s16x8*)(Bs + row * BKt + st * 8);
            }
#pragma unroll
            for (int i = 0; i < 4; i++)
#pragma unroll
                for (int j = 0; j < NJ; j++) {
                    if constexpr (BF)
                        acc[i][j] = __builtin_amdgcn_mfma_f32_16x16x32_bf16(
                            af[i], bf4[j], acc[i][j], 0, 0, 0);
                    else
                        acc[i][j] = __builtin_amdgcn_mfma_f32_16x16x32_f16(
                            __builtin_bit_cast(h16x8, af[i]),
                            __builtin_bit_cast(h16x8, bf4[j]), acc[i][j], 0, 0, 0);
                }
        }
    }

    // epilogue: C/D layout col=lane&15, row=quad*4+reg
    if constexpr (MODE == 0) {
        h16* Cb = (h16*)C + (size_t)b * cBatch;
#pragma unroll
        for (int i = 0; i < 4; i++)
#pragma unroll
            for (int j = 0; j < NJ; j++) {
                int row = m0 + wm + 16 * i + quad * 4;
                int col = n0 + wn + 16 * j + lm;
                float bN = biasN ? biasN[col] : 0.0f;
#pragma unroll
                for (int r = 0; r < 4; r++) {
                    float v = acc[i][j][r] + bN;
                    if (biasM) v += biasM[row + r];
                    Cb[(size_t)(row + r) * ldc + col] = (h16)v;
                }
            }
    } else if constexpr (MODE == 1) {
        __hip_bfloat16* Cb = (__hip_bfloat16*)C + (size_t)b * cBatch;
#pragma unroll
        for (int j = 0; j < NJ; j++) {
            int col = n0 + wn + 16 * j + lm;
            float iz = 1.0f / Z[(size_t)b * N + col];
#pragma unroll
            for (int i = 0; i < 4; i++) {
                int row = m0 + wm + 16 * i + quad * 4;
#pragma unroll
                for (int r = 0; r < 4; r++)
                    Cb[(size_t)(row + r) * ldc + col] =
                        __float2bfloat16(acc[i][j][r] * iz);
            }
        }
    } else if constexpr (MODE == 2) {
        __syncthreads();                       // fragments consumed
        float* Zl = (float*)As;
        if (tid < TN) Zl[tid] = 0.0f;
        __syncthreads();
        __hip_bfloat16* Cb = (__hip_bfloat16*)C + (size_t)b * cBatch;
#pragma unroll
        for (int j = 0; j < NJ; j++) {
            int cl = wn + 16 * j + lm;
            int col = n0 + cl;
            float zp = 0.0f;
#pragma unroll
            for (int i = 0; i < 4; i++) {
                int row = m0 + wm + 16 * i + quad * 4;
#pragma unroll
                for (int r = 0; r < 4; r++) {
                    float e = __expf(acc[i][j][r]);
                    zp += e;
                    Cb[(size_t)(row + r) * ldc + col] = __float2bfloat16(e);
                }
            }
            atomicAdd(&Zl[cl], zp);
        }
        __syncthreads();
        if (tid < TN) atomicAdd(&Z[(size_t)b * N + n0 + tid], Zl[tid]);
    } else {  // MODE 3: f16 out + biasN, fused BN sum/sumsq atomics
        __syncthreads();                       // fragments consumed
        float* Sl = (float*)As;                // [0:TN) col sums
        float* Sq = Sl + TN;                   // [TN:2TN) col sumsq
        if (tid < 2 * TN) Sl[tid] = 0.0f;
        __syncthreads();
        h16* Cb = (h16*)C + (size_t)b * cBatch;
#pragma unroll
        for (int j = 0; j < NJ; j++) {
            int cl = wn + 16 * j + lm;
            int col = n0 + cl;
            float bN = biasN[col];
            float s = 0.0f, q = 0.0f;
#pragma unroll
            for (int i = 0; i < 4; i++) {
                int row = m0 + wm + 16 * i + quad * 4;
#pragma unroll
                for (int r = 0; r < 4; r++) {
                    float v = acc[i][j][r] + bN;
                    s += v;
                    q = fmaf(v, v, q);
                    Cb[(size_t)(row + r) * ldc + col] = (h16)v;
                }
            }
            atomicAdd(&Sl[cl], s);
            atomicAdd(&Sq[cl], q);
        }
        __syncthreads();
        if (tid < TN) {
            atomicAdd(&Cp[n0 + tid], Sl[tid]);
            atomicAdd(&Z[n0 + tid], Sq[tid]);
        }
    }
}

// ---------------------------------------------------------------------------
// Fused prep: z<8  -> inpt[b][c][t] fp32 -> xT[b][t][c] f16 (64x64 transpose)
//             z==8 -> weights->f16 concat, bias3, Z/psum/pssq zero-init.
// ---------------------------------------------------------------------------
__global__ __launch_bounds__(256)
void conv_prep(const float* __restrict__ inpt, h16* __restrict__ xT,
               const float* __restrict__ w0, const float* __restrict__ w1,
               const float* __restrict__ w2, const float* __restrict__ w3,
               const float* __restrict__ tb, const float* __restrict__ pb,
               const float* __restrict__ gb,
               h16* __restrict__ dst, float* __restrict__ bias3,
               float* __restrict__ Z, float* __restrict__ psum,
               float* __restrict__ pssq) {
    const int tid = threadIdx.x;
    if (blockIdx.z == 8) {
        int bx = blockIdx.y * 32 + blockIdx.x;          // 0..255
#pragma unroll
        for (int rep = 0; rep < 2; rep++) {
            int idx4 = bx * 512 + rep * 256 + tid;
            int arr = idx4 >> 15, local4 = idx4 & 32767;
            const float* srcs[4] = {w0, w1, w2, w3};
            float4 v = ((const float4*)srcs[arr])[local4];
            h16 o[4] = {(h16)v.x, (h16)v.y, (h16)v.z, (h16)v.w};
            *(uint2*)(dst + (size_t)arr * 131072 + (size_t)local4 * 4) = *(uint2*)o;
        }
        if (bx < 64) Z[bx * 256 + tid] = 0.0f;          // 16384 floats
        if (bx == 64) bias3[tid] = tb[tid];
        if (bx == 65) bias3[256 + tid] = pb[tid];
        if (bx == 66) bias3[512 + tid] = gb[tid];
        if (bx == 67) {
            psum[tid] = 0.0f; psum[tid + 256] = 0.0f;
            pssq[tid] = 0.0f; pssq[tid + 256] = 0.0f;
        }
        return;
    }
    __shared__ float lds[64][68];
    const int b = blockIdx.z;
    const int t0 = blockIdx.x * 64, c0 = blockIdx.y * 64;
    const int q = tid >> 4, k = tid & 15;
    const float* ib = inpt + (size_t)b * Cx * Tx;
#pragma unroll
    for (int i = 0; i < 4; i++) {
        int c = q + 16 * i;
        float4 v = *(const float4*)(ib + (size_t)(c0 + c) * Tx + t0 + 4 * k);
        *(float4*)&lds[c][4 * k] = v;
    }
    __syncthreads();
    h16* xb = xT + (size_t)b * Tx * Cx;
#pragma unroll
    for (int i = 0; i < 4; i++) {
        int t = q + 16 * i;
        h16 o[4];
#pragma unroll
        for (int j = 0; j < 4; j++) o[j] = (h16)lds[4 * k + j][t];
        *(uint2*)(xb + (size_t)(t0 + t) * Cx + c0 + 4 * k) = *(uint2*)o;
    }
}

// ---------------------------------------------------------------------------
// out[b][c][t] = xT[b][t][c] + gamma[c]*(hT[b][t][c]-mu)*rsig + beta[c]
// Residual taken from the f16 xT copy (saves the 64MB fp32 inpt re-read;
// rounding <= 2^-11 relative, invisible vs 0.0625 absmax).
// BN finalize fused: mu/rsig computed inline from psum/pssq.
// ---------------------------------------------------------------------------
__global__ __launch_bounds__(256)
void bn_apply_T(const h16* __restrict__ xT, const h16* __restrict__ hT,
                const float* __restrict__ psum, const float* __restrict__ pssq,
                const float* __restrict__ gamma, const float* __restrict__ beta,
                float* __restrict__ out) {
    __shared__ float ldsH[64][68];
    __shared__ float ldsX[64][68];
    const int b = blockIdx.z, t0 = blockIdx.x * 64, c0 = blockIdx.y * 64;
    const int tid = threadIdx.x, q = tid >> 4, k = tid & 15;
    const h16* hb = hT + (size_t)b * Tx * Cx;
    const h16* xb = xT + (size_t)b * Tx * Cx;
#pragma unroll
    for (int i = 0; i < 4; i++) {
        int t = q + 16 * i;
        uint2 rh = *(const uint2*)(hb + (size_t)(t0 + t) * Cx + c0 + 4 * k);
        uint2 rx = *(const uint2*)(xb + (size_t)(t0 + t) * Cx + c0 + 4 * k);
        const h16* hp = (const h16*)&rh;
        const h16* xp = (const h16*)&rx;
        *(float4*)&ldsH[t][4 * k] =
            make_float4((float)hp[0], (float)hp[1], (float)hp[2], (float)hp[3]);
        *(float4*)&ldsX[t][4 * k] =
            make_float4((float)xp[0], (float)xp[1], (float)xp[2], (float)xp[3]);
    }
    __syncthreads();
    float* ob = out + (size_t)b * Cx * Tx;
    const float invN = 1.0f / (float)(Bx * Tx);
#pragma unroll
    for (int i = 0; i < 4; i++) {
        int c = q + 16 * i;
        int cg = c0 + c;
        float mu = psum[cg] * invN;
        float var = pssq[cg] * invN - mu * mu;
        float rv = rsqrtf(var + EPSx);
        float ga = gamma[cg], be = beta[cg];
        float4 o;
        o.x = ldsX[4 * k + 0][c] + ga * (ldsH[4 * k + 0][c] - mu) * rv + be;
        o.y = ldsX[4 * k + 1][c] + ga * (ldsH[4 * k + 1][c] - mu) * rv + be;
        o.z = ldsX[4 * k + 2][c] + ga * (ldsH[4 * k + 2][c] - mu) * rv + be;
        o.w = ldsX[4 * k + 3][c] + ga * (ldsH[4 * k + 3][c] - mu) * rv + be;
        *(float4*)(ob + (size_t)cg * Tx + t0 + 4 * k) = o;
    }
}

// ---------------------------------------------------------------------------
// Workspace (bytes, total ~121 MiB):
//   xT    @0            16,777,216  (f16 [b][t][c]; stays live for residual)
//   w4    @16,777,216    1,048,576  (theta|phi|g|ht f16; wTPG=768x512, wHt)
//   bias3 @17,825,792        3,072  (theta_b||phi_b||g_b)
//   Z     @17,828,864       65,536  (fp32 exp-row-sums [b][t])
//   psum  @17,894,400        2,048  (fp32 BN channel sums)
//   pssq  @17,896,448        2,048
//   thpg  @17,902,592   25,165,824  (f16 [b][t][theta||phi||g], ld 768;
//                                    first 16MB reused as hT after gh GEMM)
//   gh    @43,068,416   16,777,216  (bf16 gh' = (ht_w·g)/Z, [b][c][t])
//   LT    @59,845,632   67,108,864  (bf16 exp-logits [b][s][t])
// ---------------------------------------------------------------------------
extern "C" void kernel_launch(void* const* d_in, const int* in_sizes, int n_in,
                              void* d_out, int out_size, void* d_ws, size_t ws_size,
                              hipStream_t stream) {
    const float* inpt    = (const float*)d_in[0];
    const float* theta_w = (const float*)d_in[1];
    const float* theta_b = (const float*)d_in[2];
    const float* phi_w   = (const float*)d_in[3];
    const float* phi_b   = (const float*)d_in[4];
    const float* g_w     = (const float*)d_in[5];
    const float* g_b     = (const float*)d_in[6];
    const float* ht_w    = (const float*)d_in[7];
    const float* ht_b    = (const float*)d_in[8];
    const float* gamma   = (const float*)d_in[9];
    const float* beta    = (const float*)d_in[10];

    char* ws = (char*)d_ws;
    h16*   xT    = (h16*)(ws + 0);
    h16*   w4    = (h16*)(ws + 16777216);     // wTPG = w4 (768 rows x 512)
    h16*   wHt   = w4 + 393216;               // 512 rows x 256
    float* bias3 = (float*)(ws + 17825792);
    float* Z     = (float*)(ws + 17828864);
    float* psum  = (float*)(ws + 17894400);
    float* pssq  = (float*)(ws + 17896448);
    h16*   thpg  = (h16*)(ws + 17902592);
    h16*   gh    = (h16*)(ws + 43068416);     // bf16 bits
    h16*   LT    = (h16*)(ws + 59845632);     // bf16 bits
    h16*   hT    = thpg;                      // reuse: thpg dead after gh GEMM
                                              // (xT stays live for residual)

    const long sX  = (long)Tx * Cx;    // 1,048,576 (xT, hT)
    const long sTP = (long)Tx * 768;   // 1,572,864 (thpg)
    const long sGH = (long)Cx * Tx;    // 1,048,576 (gh)
    const long sW  = (long)Tx * Tx;    // 4,194,304 (LT)

    dim3 blk(256);
    // fused input transpose + weight conversion + zero-init
    conv_prep<<<dim3(Tx / 64, Cx / 64, Bx + 1), blk, 0, stream>>>(
        inpt, xT, theta_w, phi_w, g_w, ht_w, theta_b, phi_b, g_b,
        w4, bias3, Z, psum, pssq);
    // thpg[t][n] = sum_c xT[t][c]*(theta||phi||g)[n][c] + bias3[n]   (f16)
    // BK=128 (4 K-steps). grid: 8 batches x (16 m x 6 n) = 768
    gemm_mf<0, false, 128, 128><<<dim3(768), blk, 0, stream>>>(
        xT, sX, Cx, w4, 0, Cx, thpg, sTP, 768, nullptr, nullptr,
        Tx, 768, Cx, 16, nullptr, bias3);
    // LT[s][t] = exp(sum_d phi[s][d]*theta[t][d]) bf16; Z[t] += col sums
    // BK=128 (2 K-steps). grid: 8 x (16 x 16) = 2048
    gemm_mf<2, false, 128, 128><<<dim3(2048), blk, 0, stream>>>(
        thpg + 256, sTP, 768, thpg, sTP, 768, LT, sW, Tx, nullptr, Z,
        Tx, Tx, Dx, 16, nullptr, nullptr);
    // gh[c][t] = (sum_d ht_w[c][d]*g[t][d]) / Z[t]   (bf16)
    // BK=128 (2 K-steps). grid: 8 x (4 x 16) = 512
    gemm_mf<1, false, 128, 128><<<dim3(512), blk, 0, stream>>>(
        wHt, 0, Dx, thpg + 512, sTP, 768, gh, sGH, Tx, nullptr, Z,
        Cx, Tx, Dx, 4, nullptr, nullptr);
    // hT[s][c] = sum_t LT[s][t]*gh[c][t] + ht_b[c]; fused BN stat atomics
    // TN=128, BK=128, 4-bit XOR (r10: 0 conflicts). grid 512.
    gemm_mf<3, true, 128, 128><<<dim3(512), blk, 0, stream>>>(
        LT, sW, Tx, gh, sGH, Tx, hT, sX, Cx, psum, pssq,
        Tx, Cx, Tx, 16, nullptr, ht_b);
    // out = xT(residual) + BN(hT), both f16 [t][c] -> fp32 [c][t]
    bn_apply_T<<<dim3(Tx / 64, Cx / 64, Bx), blk, 0, stream>>>(
        xT, hT, psum, pssq, gamma, beta, (float*)d_out);
}

// Round 12
// 224.555 us; speedup vs baseline: 1.0351x; 1.0351x over previous
//
#include <hip/hip_runtime.h>
#include <hip/hip_bf16.h>
#include <math.h>

#define Bx 8
#define Cx 512
#define Dx 256
#define Tx 2048
#define EPSx 1e-5f

typedef _Float16 h16;
typedef __attribute__((ext_vector_type(8))) _Float16 h16x8;
typedef __attribute__((ext_vector_type(8))) short s16x8;
typedef __attribute__((ext_vector_type(4))) float f32x4;

typedef __attribute__((address_space(3))) unsigned int lds_u32;
typedef __attribute__((address_space(1))) const unsigned int glb_u32;

// async 16B global -> LDS DMA. ldsp must be wave-uniform; HW adds lane*16.
__device__ __forceinline__ void cp16(void* ldsp, const void* g) {
    __builtin_amdgcn_global_load_lds((glb_u32*)g, (lds_u32*)ldsp, 16, 0, 0);
}

// ---------------------------------------------------------------------------
// MFMA GEMM core: acc[m][n] = sum_k A[m][k]*B[n][k], 2-byte dtypes (f16/bf16),
// tile 128 x TN, K-chunk BKt, 4 waves (2x2), global_load_lds staging with
// width-matched XOR swizzle (stored_chunk = logical ^ (row & (CH-1))).
// BKt choice (r10/r11 measured): BK=128 only for long-K (>=16 K-steps, MODE-3
// K=2048; logits K=256 neutral) — 64KB LDS halves occupancy, which costs
// short-K GEMMs ~15us (m132 cliff, r11). Short-K stays BK=64 (32KB, 4 blk/CU).
// Grid: 1-D, batch->XCD swizzle b = id & 7 (r7: FETCH 147->41MB).
// Epilogue by MODE:
//   0: f16 out, + optional biasM[row] + biasN[col]                (projection)
//   1: bf16 out = acc * (1/Z[b*N+col])                            (gh' = gh/Z)
//   2: bf16 out = exp(acc); atomicAdd Z[b*N+col] += col sums      (logits)
//   3: f16 out = acc + biasN[col]; atomicAdd Cp[col]+=sum(v),
//      Z[col]+=sum(v^2) (fused BatchNorm stats)                   (big GEMM)
// ---------------------------------------------------------------------------
template<int MODE, bool BF, int TN, int BKt>
__global__ __launch_bounds__(256, 4)
void gemm_mf(const h16* __restrict__ A, long aBatch, int lda,
             const h16* __restrict__ B, long bBatch, int ldb,
             void* __restrict__ C, long cBatch, int ldc,
             float* __restrict__ Cp, float* __restrict__ Z,
             int M, int N, int K, int mBlk,
             const float* __restrict__ biasM, const float* __restrict__ biasN) {
    constexpr int NJ  = TN / 32;         // B-frags per wave (n-dir)
    constexpr int CH  = BKt / 8;         // 16B chunks per LDS row
    constexpr int RPR = 2048 / BKt;      // rows per 4KB staging round
    __shared__ h16 As[128 * BKt];
    __shared__ h16 Bs[TN * BKt];
    const int tid  = threadIdx.x;
    const int lane = tid & 63, wid = tid >> 6;
    const int wm = (wid & 1) * 64, wn = (wid >> 1) * (TN / 2);
    const int lm = lane & 15, quad = lane >> 4;
    const unsigned id = blockIdx.x;
    const int b = id & 7;
    const unsigned rr = id >> 3;
    const int m0 = (rr % (unsigned)mBlk) * 128;
    const int n0 = (rr / (unsigned)mBlk) * TN;
    const h16* Ab = A + (size_t)b * aBatch + (size_t)m0 * lda;
    const h16* Bb = B + (size_t)b * bBatch + (size_t)n0 * ldb;

    const int srow  = tid / CH;                        // row within round
    const int sclog = (tid & (CH - 1)) ^ (srow & (CH - 1));  // logical chunk
    char* ldsA = (char*)As + (tid & ~63) * 16;         // wave-uniform base
    char* ldsB = (char*)Bs + (tid & ~63) * 16;

    f32x4 acc[4][NJ] = {};

    for (int k0 = 0; k0 < K; k0 += BKt) {
        __syncthreads();   // all waves done reading previous tile
#pragma unroll
        for (int i = 0; i < 128 / RPR; i++) {
            int r = srow + RPR * i;
            cp16(ldsA + i * 4096, Ab + (size_t)r * lda + k0 + sclog * 8);
        }
#pragma unroll
        for (int i = 0; i < TN / RPR; i++) {
            int r = srow + RPR * i;
            cp16(ldsB + i * 4096, Bb + (size_t)r * ldb + k0 + sclog * 8);
        }
        __syncthreads();   // drains vmcnt(0): tile resident
#pragma unroll
        for (int ks = 0; ks < BKt / 32; ks++) {
            s16x8 af[4], bf4[NJ];
#pragma unroll
            for (int i = 0; i < 4; i++) {
                int row = wm + 16 * i + lm;
                int st = (ks * 4 + quad) ^ (lm & (CH - 1));
                af[i] = *(const s16x8*)(As + row * BKt + st * 8);
            }
#pragma unroll
            for (int j = 0; j < NJ; j++) {
                int row = wn + 16 * j + lm;
                int st = (ks * 4 + quad) ^ (lm & (CH - 1));
                bf4[j] = *(const s16x8*)(Bs + row * BKt + st * 8);
            }
#pragma unroll
            for (int i = 0; i < 4; i++)
#pragma unroll
                for (int j = 0; j < NJ; j++) {
                    if constexpr (BF)
                        acc[i][j] = __builtin_amdgcn_mfma_f32_16x16x32_bf16(
                            af[i], bf4[j], acc[i][j], 0, 0, 0);
                    else
                        acc[i][j] = __builtin_amdgcn_mfma_f32_16x16x32_f16(
                            __builtin_bit_cast(h16x8, af[i]),
                            __builtin_bit_cast(h16x8, bf4[j]), acc[i][j], 0, 0, 0);
                }
        }
    }

    // epilogue: C/D layout col=lane&15, row=quad*4+reg
    if constexpr (MODE == 0) {
        h16* Cb = (h16*)C + (size_t)b * cBatch;
#pragma unroll
        for (int i = 0; i < 4; i++)
#pragma unroll
            for (int j = 0; j < NJ; j++) {
                int row = m0 + wm + 16 * i + quad * 4;
                int col = n0 + wn + 16 * j + lm;
                float bN = biasN ? biasN[col] : 0.0f;
#pragma unroll
                for (int r = 0; r < 4; r++) {
                    float v = acc[i][j][r] + bN;
                    if (biasM) v += biasM[row + r];
                    Cb[(size_t)(row + r) * ldc + col] = (h16)v;
                }
            }
    } else if constexpr (MODE == 1) {
        __hip_bfloat16* Cb = (__hip_bfloat16*)C + (size_t)b * cBatch;
#pragma unroll
        for (int j = 0; j < NJ; j++) {
            int col = n0 + wn + 16 * j + lm;
            float iz = 1.0f / Z[(size_t)b * N + col];
#pragma unroll
            for (int i = 0; i < 4; i++) {
                int row = m0 + wm + 16 * i + quad * 4;
#pragma unroll
                for (int r = 0; r < 4; r++)
                    Cb[(size_t)(row + r) * ldc + col] =
                        __float2bfloat16(acc[i][j][r] * iz);
            }
        }
    } else if constexpr (MODE == 2) {
        __syncthreads();                       // fragments consumed
        float* Zl = (float*)As;
        if (tid < TN) Zl[tid] = 0.0f;
        __syncthreads();
        __hip_bfloat16* Cb = (__hip_bfloat16*)C + (size_t)b * cBatch;
#pragma unroll
        for (int j = 0; j < NJ; j++) {
            int cl = wn + 16 * j + lm;
            int col = n0 + cl;
            float zp = 0.0f;
#pragma unroll
            for (int i = 0; i < 4; i++) {
                int row = m0 + wm + 16 * i + quad * 4;
#pragma unroll
                for (int r = 0; r < 4; r++) {
                    float e = __expf(acc[i][j][r]);
                    zp += e;
                    Cb[(size_t)(row + r) * ldc + col] = __float2bfloat16(e);
                }
            }
            atomicAdd(&Zl[cl], zp);
        }
        __syncthreads();
        if (tid < TN) atomicAdd(&Z[(size_t)b * N + n0 + tid], Zl[tid]);
    } else {  // MODE 3: f16 out + biasN, fused BN sum/sumsq atomics
        __syncthreads();                       // fragments consumed
        float* Sl = (float*)As;                // [0:TN) col sums
        float* Sq = Sl + TN;                   // [TN:2TN) col sumsq
        if (tid < 2 * TN) Sl[tid] = 0.0f;
        __syncthreads();
        h16* Cb = (h16*)C + (size_t)b * cBatch;
#pragma unroll
        for (int j = 0; j < NJ; j++) {
            int cl = wn + 16 * j + lm;
            int col = n0 + cl;
            float bN = biasN[col];
            float s = 0.0f, q = 0.0f;
#pragma unroll
            for (int i = 0; i < 4; i++) {
                int row = m0 + wm + 16 * i + quad * 4;
#pragma unroll
                for (int r = 0; r < 4; r++) {
                    float v = acc[i][j][r] + bN;
                    s += v;
                    q = fmaf(v, v, q);
                    Cb[(size_t)(row + r) * ldc + col] = (h16)v;
                }
            }
            atomicAdd(&Sl[cl], s);
            atomicAdd(&Sq[cl], q);
        }
        __syncthreads();
        if (tid < TN) {
            atomicAdd(&Cp[n0 + tid], Sl[tid]);
            atomicAdd(&Z[n0 + tid], Sq[tid]);
        }
    }
}

// ---------------------------------------------------------------------------
// Fused prep: z<8  -> inpt[b][c][t] fp32 -> xT[b][t][c] f16 (64x64 transpose)
//             z==8 -> weights->f16 concat, bias3, Z/psum/pssq zero-init.
// ---------------------------------------------------------------------------
__global__ __launch_bounds__(256)
void conv_prep(const float* __restrict__ inpt, h16* __restrict__ xT,
               const float* __restrict__ w0, const float* __restrict__ w1,
               const float* __restrict__ w2, const float* __restrict__ w3,
               const float* __restrict__ tb, const float* __restrict__ pb,
               const float* __restrict__ gb,
               h16* __restrict__ dst, float* __restrict__ bias3,
               float* __restrict__ Z, float* __restrict__ psum,
               float* __restrict__ pssq) {
    const int tid = threadIdx.x;
    if (blockIdx.z == 8) {
        int bx = blockIdx.y * 32 + blockIdx.x;          // 0..255
#pragma unroll
        for (int rep = 0; rep < 2; rep++) {
            int idx4 = bx * 512 + rep * 256 + tid;
            int arr = idx4 >> 15, local4 = idx4 & 32767;
            const float* srcs[4] = {w0, w1, w2, w3};
            float4 v = ((const float4*)srcs[arr])[local4];
            h16 o[4] = {(h16)v.x, (h16)v.y, (h16)v.z, (h16)v.w};
            *(uint2*)(dst + (size_t)arr * 131072 + (size_t)local4 * 4) = *(uint2*)o;
        }
        if (bx < 64) Z[bx * 256 + tid] = 0.0f;          // 16384 floats
        if (bx == 64) bias3[tid] = tb[tid];
        if (bx == 65) bias3[256 + tid] = pb[tid];
        if (bx == 66) bias3[512 + tid] = gb[tid];
        if (bx == 67) {
            psum[tid] = 0.0f; psum[tid + 256] = 0.0f;
            pssq[tid] = 0.0f; pssq[tid + 256] = 0.0f;
        }
        return;
    }
    __shared__ float lds[64][68];
    const int b = blockIdx.z;
    const int t0 = blockIdx.x * 64, c0 = blockIdx.y * 64;
    const int q = tid >> 4, k = tid & 15;
    const float* ib = inpt + (size_t)b * Cx * Tx;
#pragma unroll
    for (int i = 0; i < 4; i++) {
        int c = q + 16 * i;
        float4 v = *(const float4*)(ib + (size_t)(c0 + c) * Tx + t0 + 4 * k);
        *(float4*)&lds[c][4 * k] = v;
    }
    __syncthreads();
    h16* xb = xT + (size_t)b * Tx * Cx;
#pragma unroll
    for (int i = 0; i < 4; i++) {
        int t = q + 16 * i;
        h16 o[4];
#pragma unroll
        for (int j = 0; j < 4; j++) o[j] = (h16)lds[4 * k + j][t];
        *(uint2*)(xb + (size_t)(t0 + t) * Cx + c0 + 4 * k) = *(uint2*)o;
    }
}

// ---------------------------------------------------------------------------
// out[b][c][t] = xT[b][t][c] + gamma[c]*(hT[b][t][c]-mu)*rsig + beta[c]
// Residual from the f16 xT copy (saves the 64MB fp32 inpt re-read; rounding
// <= 2^-11 relative, invisible vs 0.0625 absmax).
// BN finalize fused: mu/rsig computed inline from psum/pssq.
// ---------------------------------------------------------------------------
__global__ __launch_bounds__(256)
void bn_apply_T(const h16* __restrict__ xT, const h16* __restrict__ hT,
                const float* __restrict__ psum, const float* __restrict__ pssq,
                const float* __restrict__ gamma, const float* __restrict__ beta,
                float* __restrict__ out) {
    __shared__ float ldsH[64][68];
    __shared__ float ldsX[64][68];
    const int b = blockIdx.z, t0 = blockIdx.x * 64, c0 = blockIdx.y * 64;
    const int tid = threadIdx.x, q = tid >> 4, k = tid & 15;
    const h16* hb = hT + (size_t)b * Tx * Cx;
    const h16* xb = xT + (size_t)b * Tx * Cx;
#pragma unroll
    for (int i = 0; i < 4; i++) {
        int t = q + 16 * i;
        uint2 rh = *(const uint2*)(hb + (size_t)(t0 + t) * Cx + c0 + 4 * k);
        uint2 rx = *(const uint2*)(xb + (size_t)(t0 + t) * Cx + c0 + 4 * k);
        const h16* hp = (const h16*)&rh;
        const h16* xp = (const h16*)&rx;
        *(float4*)&ldsH[t][4 * k] =
            make_float4((float)hp[0], (float)hp[1], (float)hp[2], (float)hp[3]);
        *(float4*)&ldsX[t][4 * k] =
            make_float4((float)xp[0], (float)xp[1], (float)xp[2], (float)xp[3]);
    }
    __syncthreads();
    float* ob = out + (size_t)b * Cx * Tx;
    const float invN = 1.0f / (float)(Bx * Tx);
#pragma unroll
    for (int i = 0; i < 4; i++) {
        int c = q + 16 * i;
        int cg = c0 + c;
        float mu = psum[cg] * invN;
        float var = pssq[cg] * invN - mu * mu;
        float rv = rsqrtf(var + EPSx);
        float ga = gamma[cg], be = beta[cg];
        float4 o;
        o.x = ldsX[4 * k + 0][c] + ga * (ldsH[4 * k + 0][c] - mu) * rv + be;
        o.y = ldsX[4 * k + 1][c] + ga * (ldsH[4 * k + 1][c] - mu) * rv + be;
        o.z = ldsX[4 * k + 2][c] + ga * (ldsH[4 * k + 2][c] - mu) * rv + be;
        o.w = ldsX[4 * k + 3][c] + ga * (ldsH[4 * k + 3][c] - mu) * rv + be;
        *(float4*)(ob + (size_t)cg * Tx + t0 + 4 * k) = o;
    }
}

// ---------------------------------------------------------------------------
// Workspace (bytes, total ~121 MiB):
//   xT    @0            16,777,216  (f16 [b][t][c]; stays live for residual)
//   w4    @16,777,216    1,048,576  (theta|phi|g|ht f16; wTPG=768x512, wHt)
//   bias3 @17,825,792        3,072  (theta_b||phi_b||g_b)
//   Z     @17,828,864       65,536  (fp32 exp-row-sums [b][t])
//   psum  @17,894,400        2,048  (fp32 BN channel sums)
//   pssq  @17,896,448        2,048
//   thpg  @17,902,592   25,165,824  (f16 [b][t][theta||phi||g], ld 768;
//                                    first 16MB reused as hT after gh GEMM)
//   gh    @43,068,416   16,777,216  (bf16 gh' = (ht_w·g)/Z, [b][c][t])
//   LT    @59,845,632   67,108,864  (bf16 exp-logits [b][s][t])
// ---------------------------------------------------------------------------
extern "C" void kernel_launch(void* const* d_in, const int* in_sizes, int n_in,
                              void* d_out, int out_size, void* d_ws, size_t ws_size,
                              hipStream_t stream) {
    const float* inpt    = (const float*)d_in[0];
    const float* theta_w = (const float*)d_in[1];
    const float* theta_b = (const float*)d_in[2];
    const float* phi_w   = (const float*)d_in[3];
    const float* phi_b   = (const float*)d_in[4];
    const float* g_w     = (const float*)d_in[5];
    const float* g_b     = (const float*)d_in[6];
    const float* ht_w    = (const float*)d_in[7];
    const float* ht_b    = (const float*)d_in[8];
    const float* gamma   = (const float*)d_in[9];
    const float* beta    = (const float*)d_in[10];

    char* ws = (char*)d_ws;
    h16*   xT    = (h16*)(ws + 0);
    h16*   w4    = (h16*)(ws + 16777216);     // wTPG = w4 (768 rows x 512)
    h16*   wHt   = w4 + 393216;               // 512 rows x 256
    float* bias3 = (float*)(ws + 17825792);
    float* Z     = (float*)(ws + 17828864);
    float* psum  = (float*)(ws + 17894400);
    float* pssq  = (float*)(ws + 17896448);
    h16*   thpg  = (h16*)(ws + 17902592);
    h16*   gh    = (h16*)(ws + 43068416);     // bf16 bits
    h16*   LT    = (h16*)(ws + 59845632);     // bf16 bits
    h16*   hT    = thpg;                      // reuse: thpg dead after gh GEMM
                                              // (xT stays live for residual)

    const long sX  = (long)Tx * Cx;    // 1,048,576 (xT, hT)
    const long sTP = (long)Tx * 768;   // 1,572,864 (thpg)
    const long sGH = (long)Cx * Tx;    // 1,048,576 (gh)
    const long sW  = (long)Tx * Tx;    // 4,194,304 (LT)

    dim3 blk(256);
    // fused input transpose + weight conversion + zero-init
    conv_prep<<<dim3(Tx / 64, Cx / 64, Bx + 1), blk, 0, stream>>>(
        inpt, xT, theta_w, phi_w, g_w, ht_w, theta_b, phi_b, g_b,
        w4, bias3, Z, psum, pssq);
    // thpg[t][n] = sum_c xT[t][c]*(theta||phi||g)[n][c] + bias3[n]   (f16)
    // BK=64 (short K: keep 32KB LDS / 4 blk/CU — r11 cliff lesson). grid 768.
    gemm_mf<0, false, 128, 64><<<dim3(768), blk, 0, stream>>>(
        xT, sX, Cx, w4, 0, Cx, thpg, sTP, 768, nullptr, nullptr,
        Tx, 768, Cx, 16, nullptr, bias3);
    // LT[s][t] = exp(sum_d phi[s][d]*theta[t][d]) bf16; Z[t] += col sums
    // BK=128 (neutral-to-positive at K=256 with 2048-block grid). grid 2048.
    gemm_mf<2, false, 128, 128><<<dim3(2048), blk, 0, stream>>>(
        thpg + 256, sTP, 768, thpg, sTP, 768, LT, sW, Tx, nullptr, Z,
        Tx, Tx, Dx, 16, nullptr, nullptr);
    // gh[c][t] = (sum_d ht_w[c][d]*g[t][d]) / Z[t]   (bf16)
    // BK=64 (short K). grid: 8 x (4 x 16) = 512
    gemm_mf<1, false, 128, 64><<<dim3(512), blk, 0, stream>>>(
        wHt, 0, Dx, thpg + 512, sTP, 768, gh, sGH, Tx, nullptr, Z,
        Cx, Tx, Dx, 4, nullptr, nullptr);
    // hT[s][c] = sum_t LT[s][t]*gh[c][t] + ht_b[c]; fused BN stat atomics
    // TN=128, BK=128 (long K amortizes; r10: 0 conflicts). grid 512.
    gemm_mf<3, true, 128, 128><<<dim3(512), blk, 0, stream>>>(
        LT, sW, Tx, gh, sGH, Tx, hT, sX, Cx, psum, pssq,
        Tx, Cx, Tx, 16, nullptr, ht_b);
    // out = xT(residual) + BN(hT), both f16 [t][c] -> fp32 [c][t]
    bn_apply_T<<<dim3(Tx / 64, Cx / 64, Bx), blk, 0, stream>>>(
        xT, hT, psum, pssq, gamma, beta, (float*)d_out);
}